// Round 1
// baseline (108.112 us; speedup 1.0000x reference)
//
#include <hip/hip_runtime.h>
#include <math.h>

#define NW 14
#define NSTATE 16384
#define HALF 8192
#define NL 4
#define BATCH 128
#define TPB 1024
#define SHB1 (84 * 1024)   // force 1 blk/CU: 256 blocks -> 256 distinct CUs

// ---------------------------------------------------------------------------
// Wire w <-> index bit (13-w). Ring composite R (verified r1):
//   y_p = x_p^x_{p+1} (p<=11), y12 = x12^x13^x0, y13 = x13^x0.
//
// r13 = r12 restructured for FULL-GRID tail. Previous k_rest ran 128 blocks
// on 256 CUs (half the chip idle for ~3/4 of the runtime). Split it into two
// 256-block half-state kernels using the verified exit/entry relabel
// contract (k_layer1 -> k_rest, absmax 0.0):
//   k_mid : entry(deferred G[1,0]) + layer-2 pass3h x4 + exit_scatter(G[2,1])
//           -> SB.  (exit/entry pair replaces passE; gauge is layer-
//           independent: k_rest used identical pass templates for L2 and L3.)
//   k_last: entry folds deferred G[2,0] (pairs ^0x1FFF per half, rc twiddle,
//           verbatim k_rest entry) THEN G[3,0] (plain butterfly across the
//           two SB halves, keep row h). G[3,0] commutes exactly with the
//           later ops: pass3h twiddles read only state bits 4..6, g1 acts on
//           bit 12 -- all identical on both bit-13 sheets. Then layer-3
//           pass3h x4 + k_rest's contraction restricted to the half
//           (k = kk | h<<1), atomicAdd partials into out[b] (init'd by k_mid).
// Cost: +1 launch, +16MB SB write, +32MB SB read (2x redundant 4-group).
// Gain: the 128-CU tail (~3/4 of total) now runs on all 256 CUs.
// ---------------------------------------------------------------------------

#define B12_ 0x3FFFu
#define B13_ 0x1FFFu

// Compile-time scheduling fence only (no runtime cost).
#define WAVE_FENCE() __builtin_amdgcn_wave_barrier()

__device__ __forceinline__ unsigned sxmap(unsigned v) {   // v: bits 0..11
    unsigned t = v;
    t ^= t >> 1; t ^= t >> 2; t ^= t >> 4; t ^= t >> 8;
    return (t & 0x0FFFu) | ((t & 1u) << 13);              // = Rinv(v)
}

__device__ __forceinline__ float2 cmul(float2 u, float2 v) {
    return make_float2(u.x * v.x - u.y * v.y, u.x * v.y + u.y * v.x);
}

// Fused 1q gate G = RZ(t2)*RX(t1) (layer 0 folds data RX; verified r1-r11).
__device__ __forceinline__ float4 fused_coef(const float* weights,
                                             const float* states,
                                             int b, int l, int w) {
    float t1 = weights[(l * NW + w) * 2 + 0];
    float t2 = weights[(l * NW + w) * 2 + 1];
    if (l == 0) t1 += fabsf(states[(size_t)b * NSTATE + w]);
    float s, c, sz, cz;
    sincosf(0.5f * t1, &s, &c);
    sincosf(0.5f * t2, &sz, &cz);
    return make_float4(c * cz, -c * sz, -s * sz, -s * cz);
}

// SU(2) gate on register pairs (k,k|M); s3&M -> X-conjugated (verified r3+).
template<int N, int M>
__device__ __forceinline__ void gateN(float2* r, float4 g, unsigned s3) {
    const float f = (s3 & (unsigned)M) ? -1.0f : 1.0f;
    g.y *= f;
    g.z *= f;
#pragma unroll
    for (int k = 0; k < N; ++k) {
        if ((k & M) == 0) {
            const float x0 = r[k].x,   y0 = r[k].y;
            const float x1 = r[k|M].x, y1 = r[k|M].y;
            r[k].x   =  g.x*x0 - g.y*y0 + g.z*x1 - g.w*y1;
            r[k].y   =  g.x*y0 + g.y*x0 + g.z*y1 + g.w*x1;
            r[k|M].x = -g.z*x0 - g.w*y0 + g.x*x1 + g.y*y1;
            r[k|M].y = -g.z*y0 + g.w*x0 + g.x*y1 - g.y*x1;
        }
    }
}

// 3-bit pass over the 13-bit HALF-state (r9 verbatim).
template<int J0, int S3SH, int S3MSK>
__device__ __forceinline__ void pass3h(float2* psi, const float4* gc,
                                       unsigned t) {
    const float4 gA = gc[13 - (J0 + 0)];
    const float4 gB = gc[13 - (J0 + 1)];
    const float4 gC = gc[13 - (J0 + 2)];
    const unsigned s3   = (t >> S3SH) & (unsigned)S3MSK;
    const unsigned low  = t & ((1u << J0) - 1u);
    const unsigned high = (t >> J0) << (J0 + 3);
    float2 r[8];
#pragma unroll
    for (int k = 0; k < 8; ++k)
        r[k] = psi[low | (((unsigned)k ^ s3) << J0) | high];
    gateN<8,1>(r, gA, s3);
    gateN<8,2>(r, gB, s3);
    gateN<8,4>(r, gC, s3);
#pragma unroll
    for (int k = 0; k < 8; ++k)
        psi[low | (((unsigned)k ^ s3) << J0) | high] = r[k];
}

// Half-state exit: wire-1 (bit12) gate + Rinv-relabel scatter (r9 verbatim).
__device__ __forceinline__ void exit_scatter(const float2* psi,
                                             float2* __restrict__ dst,
                                             float4 g1, unsigned q,
                                             unsigned tid) {
#pragma unroll
    for (int m = 0; m < 4; ++m) {
        const unsigned jc = tid + (unsigned)m * TPB;  // bits 0..11
        const float2 x0 = psi[jc];
        const float2 x1 = psi[jc | 0x1000u];
        float2 A0, A1;
        A0.x =  g1.x*x0.x - g1.y*x0.y + g1.z*x1.x - g1.w*x1.y;
        A0.y =  g1.x*x0.y + g1.y*x0.x + g1.z*x1.y + g1.w*x1.x;
        A1.x = -g1.z*x0.x - g1.w*x0.y + g1.x*x1.x + g1.y*x1.y;
        A1.y = -g1.z*x0.y + g1.w*x0.x + g1.x*x1.y - g1.y*x1.x;
        const unsigned d0 = sxmap(jc) ^ (q ? 0x1FFFu : 0u);
        dst[d0]           = A0;
        dst[d0 ^ 0x3FFFu] = A1;   // ^Rinv(e12)
    }
}

// D1: layer-0 product synth + layer-1 + exit -> SA (r9 verbatim, barriers
// between wave-local passes elided).
__global__ __launch_bounds__(TPB) void k_layer1(
    const float* __restrict__ states, const float* __restrict__ weights,
    float2* __restrict__ Sout)
{
    extern __shared__ float2 psi[];   // HALF float2 = 64 KB (84 KB requested)
    __shared__ float2 vfac[NW][2];
    __shared__ float2 T1[128];
    __shared__ float2 T2[128];
    __shared__ float4 gc[NW];
    const unsigned gid = blockIdx.x, q = gid >> 7, b = gid & 127u;
    const unsigned tid = threadIdx.x;

    if (tid < NW) {
        float4 g = fused_coef(weights, states, (int)b, 0, (int)tid);
        vfac[tid][0] = make_float2(g.x, g.y);
        vfac[tid][1] = make_float2(-g.z, g.w);
    }
    if (tid >= 64 && tid < 64 + NW)
        gc[tid - 64] = fused_coef(weights, states, (int)b, 1, (int)(tid - 64));
    __syncthreads();
    if (tid < 128) {
        float2 p = make_float2(1.0f, 0.0f);
#pragma unroll
        for (int j = 0; j < 7; ++j)
            p = cmul(p, vfac[13 - j][(tid >> j) & 1u]);
        T1[tid] = p;
    } else if (tid < 256) {
        const unsigned u = tid - 128;
        float2 p = make_float2(1.0f, 0.0f);
#pragma unroll
        for (int j = 7; j < 14; ++j)
            p = cmul(p, vfac[13 - j][(u >> (j - 7)) & 1u]);
        T2[u] = p;
    }
    __syncthreads();

#pragma unroll
    for (int m = 0; m < 8; ++m) {
        const unsigned I  = tid + (unsigned)m * TPB;
        const unsigned If = I | (q << 13);
        const unsigned lo  = (If ^ (If >> 1)) & 0x0FFFu;
        const unsigned y12 = ((If >> 12) ^ (If >> 13) ^ If) & 1u;
        const unsigned y13 = ((If >> 13) ^ If) & 1u;
        const unsigned J = lo | (y12 << 12) | (y13 << 13);
        psi[I] = cmul(T1[J & 127u], T2[J >> 7]);
    }
    __syncthreads();                       // synth is cross-wave

    pass3h<0, 1, 7>(psi, gc, tid);  WAVE_FENCE();   // exch: tid bits 0-2
    pass3h<3, 3, 1>(psi, gc, tid);  WAVE_FENCE();   // exch: tid bits 3-5
    pass3h<6, 0, 0>(psi, gc, tid);  __syncthreads(); // next exch: bits 6-8
    pass3h<9, 0, 0>(psi, gc, tid);  __syncthreads();

    exit_scatter(psi, Sout + (size_t)b * NSTATE, gc[1], q, tid);
}

// D2: half-state layer 2 (256 blocks). Entry consumes SA's deferred layer-1
// wire-0 gate (k_rest r11 entry, restricted to this block's half q); four
// local passes; exit_scatter with layer-2 wire-1 gate -> SB (deferring
// layer-2 wire-0). Also initializes out[b] = head_b for k_last's atomics.
__global__ __launch_bounds__(TPB) void k_mid(
    const float* __restrict__ states, const float* __restrict__ weights,
    const float* __restrict__ head_b,
    const float2* __restrict__ Sin, float2* __restrict__ Sout,
    float* __restrict__ out)
{
    extern __shared__ float2 psi[];   // HALF float2 = 64 KB
    __shared__ float4 gcx[NW + 1];    // [0..13] layer-2, [14] = G[1,0]
    const unsigned gid = blockIdx.x, q = gid >> 7, b = gid & 127u;
    const unsigned tid = threadIdx.x;

    if (tid < NW) gcx[tid] = fused_coef(weights, states, (int)b, 2, (int)tid);
    if (tid == 64) gcx[NW] = fused_coef(weights, states, (int)b, 1, 0);
    if (q == 0 && tid == 96) out[b] = head_b[0];   // init accumulator
    __syncthreads();

    {   // entry: deferred layer-1 wire-0 gate (pairs ^0x1FFF within half q)
        const float4 ge = gcx[NW];
        const float2* src = Sin + (size_t)b * NSTATE + (size_t)q * HALF;
#pragma unroll
        for (int m = 0; m < 4; ++m) {
            const unsigned ic = tid + (unsigned)m * TPB;   // bit12 = 0
            const float2 f0 = src[ic];
            const float2 f1 = src[ic ^ 0x1FFFu];
            const unsigned rc = (q ^ ic) & 1u;
            const float aar = ge.x, aai = rc ? -ge.y : ge.y;
            const float bbr = rc ? -ge.z : ge.z, bbi = ge.w;
            float2 oc, op;
            oc.x = aar*f0.x - aai*f0.y + bbr*f1.x - bbi*f1.y;
            oc.y = aar*f0.y + aai*f0.x + bbr*f1.y + bbi*f1.x;
            op.x = aar*f1.x + aai*f1.y - (bbr*f0.x + bbi*f0.y);
            op.y = aar*f1.y - aai*f1.x - (bbr*f0.y - bbi*f0.x);
            psi[ic]           = oc;
            psi[ic ^ 0x1FFFu] = op;
        }
    }
    __syncthreads();                       // entry is cross-wave

    pass3h<0, 1, 7>(psi, gcx, tid);  WAVE_FENCE();
    pass3h<3, 3, 1>(psi, gcx, tid);  WAVE_FENCE();
    pass3h<6, 0, 0>(psi, gcx, tid);  __syncthreads();
    pass3h<9, 0, 0>(psi, gcx, tid);  __syncthreads();

    exit_scatter(psi, Sout + (size_t)b * NSTATE, gcx[1], q, tid);
}

// D3: half-state layer 3 + contraction (256 blocks, half = post-ring wire-0
// value h). Entry folds the deferred layer-2 wire-0 gate and layer-3's
// wire-0 gate (row h of the cross-half butterfly); pass3h x4 for wires
// 13..2; wire-1 gate + cv contraction; atomicAdd partial into out[b].
__global__ __launch_bounds__(TPB) void k_last(
    const float* __restrict__ states, const float* __restrict__ weights,
    const float* __restrict__ head_w,
    const float2* __restrict__ Sin, float* __restrict__ out)
{
    extern __shared__ float2 psi[];   // HALF float2 = 64 KB
    __shared__ float4 gcx[NW + 1];    // [0..13] layer-3, [14] = G[2,0]
    __shared__ float wsum[TPB / 64];
    const unsigned gid = blockIdx.x, h = gid >> 7, b = gid & 127u;
    const unsigned tid = threadIdx.x;

    if (tid < NW) gcx[tid] = fused_coef(weights, states, (int)b, 3, (int)tid);
    if (tid == 64) gcx[NW] = fused_coef(weights, states, (int)b, 2, 0);
    __syncthreads();

    {   // entry: G[2,0] per half (rc twiddle) then G[3,0] across halves
        const float4 ge = gcx[NW];    // deferred layer-2 wire 0
        const float4 g0 = gcx[0];     // layer-3 wire 0
        // row h of G[3,0]: out_h = (ar+i*ai)*in(q=0) + (br+i*bi)*in(q=1)
        const float ar = h ? -g0.z : g0.x;
        const float ai = h ?  g0.w : g0.y;
        const float br = h ?  g0.x : g0.z;
        const float bi = h ? -g0.y : g0.w;
        const float2* s0 = Sin + (size_t)b * NSTATE;
        const float2* s1 = s0 + HALF;
#pragma unroll
        for (int m = 0; m < 4; ++m) {
            const unsigned ic = tid + (unsigned)m * TPB;   // bit12 = 0
            const unsigned jc = ic ^ 0x1FFFu;              // bit12 = 1
            const float2 f00 = s0[ic], f01 = s0[jc];
            const float2 f10 = s1[ic], f11 = s1[jc];
            const unsigned rc = ic & 1u;                   // q=0 twiddle
            float2 oc0, op0, oc1, op1;
            {   // G[2,0] on q=0 pair (rc)
                const float aar = ge.x, aai = rc ? -ge.y : ge.y;
                const float bbr = rc ? -ge.z : ge.z, bbi = ge.w;
                oc0.x = aar*f00.x - aai*f00.y + bbr*f01.x - bbi*f01.y;
                oc0.y = aar*f00.y + aai*f00.x + bbr*f01.y + bbi*f01.x;
                op0.x = aar*f01.x + aai*f01.y - (bbr*f00.x + bbi*f00.y);
                op0.y = aar*f01.y - aai*f01.x - (bbr*f00.y - bbi*f00.x);
            }
            {   // G[2,0] on q=1 pair (rc^1)
                const unsigned rx = rc ^ 1u;
                const float aar = ge.x, aai = rx ? -ge.y : ge.y;
                const float bbr = rx ? -ge.z : ge.z, bbi = ge.w;
                oc1.x = aar*f10.x - aai*f10.y + bbr*f11.x - bbi*f11.y;
                oc1.y = aar*f10.y + aai*f10.x + bbr*f11.y + bbi*f11.x;
                op1.x = aar*f11.x + aai*f11.y - (bbr*f10.x + bbi*f10.y);
                op1.y = aar*f11.y - aai*f11.x - (bbr*f10.y - bbi*f10.x);
            }
            float2 oA, oB;   // G[3,0] row h
            oA.x = ar*oc0.x - ai*oc0.y + br*oc1.x - bi*oc1.y;
            oA.y = ar*oc0.y + ai*oc0.x + br*oc1.y + bi*oc1.x;
            oB.x = ar*op0.x - ai*op0.y + br*op1.x - bi*op1.y;
            oB.y = ar*op0.y + ai*op0.x + br*op1.y + bi*op1.x;
            psi[ic] = oA;
            psi[jc] = oB;
        }
    }
    __syncthreads();                       // entry is cross-wave

    pass3h<0, 1, 7>(psi, gcx, tid);  WAVE_FENCE();
    pass3h<3, 3, 1>(psi, gcx, tid);  WAVE_FENCE();
    pass3h<6, 0, 0>(psi, gcx, tid);  __syncthreads();
    pass3h<9, 0, 0>(psi, gcx, tid);  __syncthreads();

    // wire-1 gate + contraction (k_rest r11 contraction, k = kk | h<<1)
    float hw[NW];
#pragma unroll
    for (int i = 0; i < NW; ++i) hw[i] = head_w[i];
    float H = 0.0f, H12 = 0.0f;
#pragma unroll
    for (int i = 0; i < NW; ++i) H += hw[i];
#pragma unroll
    for (int i = 2; i < NW; ++i) H12 += hw[i];

    const float4 g1 = gcx[1];   // layer-3 wire 1 (bit12)
    float acc = 0.0f;
#pragma unroll
    for (int m2 = 0; m2 < 4; ++m2) {
        const unsigned base = tid | ((unsigned)m2 << 10);  // bits 0..11
        float2 r[2];
        r[0] = psi[base];
        r[1] = psi[base | 0x1000u];
        gateN<2,1>(r, g1, 0u);
        float A = 0.0f;
        unsigned sfx = 0u;
#pragma unroll
        for (int p = 11; p >= 0; --p) {
            sfx ^= (base >> p) & 1u;
            if (sfx) A += hw[13 - p];
        }
        const unsigned P = sfx;
#pragma unroll
        for (int kk = 0; kk < 2; ++kk) {
            const unsigned u   = (unsigned)kk ^ h;   // J12 ^ J13
            const unsigned b13 = P ^ (unsigned)kk;   // parity J0..J12
            float sum = u ? (H12 - A) : A;
            if (u)   sum += hw[1];
            if (b13) sum += hw[0];
            const float cv = H - 2.0f * sum;
            acc += (r[kk].x * r[kk].x + r[kk].y * r[kk].y) * cv;
        }
    }
#pragma unroll
    for (int off = 32; off > 0; off >>= 1)
        acc += __shfl_down(acc, off, 64);
    if ((tid & 63u) == 0) wsum[tid >> 6] = acc;
    __syncthreads();
    if (tid == 0) {
        float tot = 0.0f;
#pragma unroll
        for (int i = 0; i < TPB / 64; ++i) tot += wsum[i];
        atomicAdd(out + b, tot);
    }
}

extern "C" void kernel_launch(void* const* d_in, const int* in_sizes, int n_in,
                              void* d_out, int out_size, void* d_ws, size_t ws_size,
                              hipStream_t stream) {
    const float* states  = (const float*)d_in[0];  // (128, 16384)
    const float* weights = (const float*)d_in[1];  // (4, 14, 2)
    const float* head_w  = (const float*)d_in[2];  // (1, 14)
    const float* head_b  = (const float*)d_in[3];  // (1,)
    float* out = (float*)d_out;                    // (128,)

    float2* SA = (float2*)d_ws;                        // 16 MB
    float2* SB = SA + (size_t)BATCH * NSTATE;          // next 16 MB

    k_layer1<<<2 * BATCH, TPB, SHB1, stream>>>(states, weights, SA);
    k_mid   <<<2 * BATCH, TPB, SHB1, stream>>>(states, weights, head_b,
                                               SA, SB, out);
    k_last  <<<2 * BATCH, TPB, SHB1, stream>>>(states, weights, head_w,
                                               SB, out);
}